// Round 1
// baseline (2484.277 us; speedup 1.0000x reference)
//
#include <hip/hip_runtime.h>
#include <math.h>

#define NEG_SLOPE 0.2f

__device__ __forceinline__ unsigned fkey(float f) {
    unsigned u = __float_as_uint(f);
    return (u & 0x80000000u) ? ~u : (u | 0x80000000u);
}
__device__ __forceinline__ float funkey(unsigned k) {
    unsigned u = (k & 0x80000000u) ? (k & 0x7FFFFFFFu) : ~k;
    return __uint_as_float(u);
}
__device__ __forceinline__ void atomAddF(float* p, float v) {
    unsafeAtomicAdd(p, v);  // HW global_atomic_add_f32
}
__device__ __forceinline__ float lrelu(float x) { return x > 0.f ? x : NEG_SLOPE * x; }
__device__ __forceinline__ float elu1(float x) { return x > 0.f ? x : expf(x) - 1.f; }

// ---- K0: in-degree + edge_attr sum per dst (for self-loop attr 'mean') ----
__global__ void k0_deg(const int* __restrict__ dst, const float* __restrict__ ea,
                       float* __restrict__ deg, float* __restrict__ asum, int E) {
    int t = blockIdx.x * blockDim.x + threadIdx.x;
    if (t >= E) return;
    int d = dst[t];
    atomAddF(&deg[d], 1.0f);
    atomAddF(&asum[d], ea[t]);
}

// ---- K1: xl1 = x@Wl1+bl1, xr1 = x@Wr1+br1 ; loop_attr = asum/max(deg,1) ----
__global__ void k1_node(const float* __restrict__ x,
                        const float* __restrict__ Wl, const float* __restrict__ bl,
                        const float* __restrict__ Wr, const float* __restrict__ br,
                        const float* __restrict__ deg,
                        float* __restrict__ xl, float* __restrict__ xr,
                        float* __restrict__ lattr, int N) {
    int tid = blockIdx.x * blockDim.x + threadIdx.x;
    int n = tid >> 6, d = tid & 63;
    if (n >= N) return;
    float x0 = x[2 * n], x1 = x[2 * n + 1];
    xl[tid] = x0 * Wl[d] + x1 * Wl[64 + d] + bl[d];
    xr[tid] = x0 * Wr[d] + x1 * Wr[64 + d] + br[d];
    if (d == 0) lattr[n] = lattr[n] / fmaxf(deg[n], 1.0f);
}

// ---- K2a: layer-1 logits + segment max (one wave per edge; lane = h*32+c) ----
__global__ void k2a(const float* __restrict__ xl, const float* __restrict__ xr,
                    const int* __restrict__ srcA, const int* __restrict__ dstA,
                    const float* __restrict__ ea, const float* __restrict__ lattr,
                    const float* __restrict__ We, const float* __restrict__ att,
                    float* __restrict__ logit, unsigned* __restrict__ amax,
                    int E, int Et) {
    int wv = blockIdx.x * (blockDim.x >> 6) + (threadIdx.x >> 6);
    int lane = threadIdx.x & 63;
    if (wv >= Et) return;
    int s, d; float eav;
    if (wv < E) { s = srcA[wv]; d = dstA[wv]; eav = ea[wv]; }
    else        { s = d = wv - E; eav = lattr[s]; }
    float m = xl[(size_t)s * 64 + lane] + xr[(size_t)d * 64 + lane] + eav * We[lane];
    m = lrelu(m);
    float p = m * att[lane];
    p += __shfl_xor(p, 16);
    p += __shfl_xor(p, 8);
    p += __shfl_xor(p, 4);
    p += __shfl_xor(p, 2);
    p += __shfl_xor(p, 1);
    if ((lane & 31) == 0) {
        int h = lane >> 5;
        logit[(size_t)wv * 2 + h] = p;
        atomicMax(&amax[d * 2 + h], fkey(p));
    }
}

// ---- K2b: expv, denom += expv, agg[dst] += expv * xl[src] ----
__global__ void k2b(const float* __restrict__ xl,
                    const int* __restrict__ srcA, const int* __restrict__ dstA,
                    const float* __restrict__ logit, const unsigned* __restrict__ amax,
                    float* __restrict__ denom, float* __restrict__ agg, int E, int Et) {
    int wv = blockIdx.x * (blockDim.x >> 6) + (threadIdx.x >> 6);
    int lane = threadIdx.x & 63;
    if (wv >= Et) return;
    int s, d;
    if (wv < E) { s = srcA[wv]; d = dstA[wv]; }
    else        { s = d = wv - E; }
    int h = lane >> 5;
    float ev = expf(logit[(size_t)wv * 2 + h] - funkey(amax[d * 2 + h]));
    if ((lane & 31) == 0) atomAddF(&denom[d * 2 + h], ev);
    atomAddF(&agg[(size_t)d * 64 + lane], ev * xl[(size_t)s * 64 + lane]);
}

// ---- K3a: h = agg/denom + bias1 + x@skipW + skip_b ; accumulate BN sums ----
__global__ void k3a(const float* __restrict__ x, const float* __restrict__ denom,
                    const float* __restrict__ bias1, const float* __restrict__ skW,
                    const float* __restrict__ skb,
                    float* __restrict__ h,
                    float* __restrict__ bnsum, float* __restrict__ bnsq, int N) {
    __shared__ float sv[256], sq[256];
    int tid = blockIdx.x * blockDim.x + threadIdx.x;
    int n = tid >> 6, d = tid & 63;
    float hv = 0.f;
    bool valid = (n < N);
    if (valid) {
        hv = h[tid] / (denom[n * 2 + (d >> 5)] + 1e-16f) + bias1[d]
           + x[2 * n] * skW[d] + x[2 * n + 1] * skW[64 + d] + skb[d];
        h[tid] = hv;
    }
    sv[threadIdx.x] = valid ? hv : 0.f;
    sq[threadIdx.x] = valid ? hv * hv : 0.f;
    __syncthreads();
    if (threadIdx.x < 64) {
        float s = sv[threadIdx.x] + sv[threadIdx.x + 64] + sv[threadIdx.x + 128] + sv[threadIdx.x + 192];
        float q = sq[threadIdx.x] + sq[threadIdx.x + 64] + sq[threadIdx.x + 128] + sq[threadIdx.x + 192];
        atomAddF(&bnsum[threadIdx.x], s);
        atomAddF(&bnsq[threadIdx.x], q);
    }
}

// ---- K3b: mu, rstd ----
__global__ void k3b(const float* __restrict__ bnsum, const float* __restrict__ bnsq,
                    float* __restrict__ mu, float* __restrict__ rstd, int N) {
    int d = threadIdx.x;
    float m = bnsum[d] / (float)N;
    float v = bnsq[d] / (float)N - m * m;
    mu[d] = m;
    rstd[d] = rsqrtf(v + 1e-5f);
}

// ---- K3c: BN + ELU -> xl2 = h@Wl2+bl2, xr2 = h@Wr2+br2 (wave per node) ----
__global__ void k3c(const float* __restrict__ h, const float* __restrict__ mu,
                    const float* __restrict__ rstd, const float* __restrict__ gamma,
                    const float* __restrict__ beta,
                    const float* __restrict__ Wl, const float* __restrict__ bl,
                    const float* __restrict__ Wr, const float* __restrict__ br,
                    float* __restrict__ xl2, float* __restrict__ xr2, int N) {
    __shared__ float sh[4][64];
    int w = threadIdx.x >> 6, lane = threadIdx.x & 63;
    int n = blockIdx.x * 4 + w;
    bool valid = (n < N);
    if (valid) {
        float hv = h[(size_t)n * 64 + lane];
        hv = (hv - mu[lane]) * rstd[lane] * gamma[lane] + beta[lane];
        sh[w][lane] = elu1(hv);
    }
    __syncthreads();
    if (!valid) return;
    int c = lane & 31;
    const float* W = (lane < 32) ? Wl : Wr;
    const float* b = (lane < 32) ? bl : br;
    float acc = b[c];
    #pragma unroll
    for (int k = 0; k < 64; ++k) acc += sh[w][k] * W[k * 32 + c];
    ((lane < 32) ? xl2 : xr2)[(size_t)n * 32 + c] = acc;
}

// ---- K4a: layer-2 logits + segment max (2 edges per wave, 32 lanes each) ----
__global__ void k4a(const float* __restrict__ xl2, const float* __restrict__ xr2,
                    const int* __restrict__ srcA, const int* __restrict__ dstA,
                    const float* __restrict__ ea, const float* __restrict__ lattr,
                    const float* __restrict__ We, const float* __restrict__ att,
                    float* __restrict__ logit, unsigned* __restrict__ amax,
                    int E, int Et) {
    int t = blockIdx.x * (blockDim.x >> 5) + (threadIdx.x >> 5);
    int c = threadIdx.x & 31;
    if (t >= Et) return;
    int s, d; float eav;
    if (t < E) { s = srcA[t]; d = dstA[t]; eav = ea[t]; }
    else       { s = d = t - E; eav = lattr[s]; }
    float m = xl2[(size_t)s * 32 + c] + xr2[(size_t)d * 32 + c] + eav * We[c];
    m = lrelu(m);
    float p = m * att[c];
    p += __shfl_xor(p, 16);
    p += __shfl_xor(p, 8);
    p += __shfl_xor(p, 4);
    p += __shfl_xor(p, 2);
    p += __shfl_xor(p, 1);
    if (c == 0) {
        logit[t] = p;
        atomicMax(&amax[d], fkey(p));
    }
}

// ---- K4b: expv (stored in place of logit), denom, agg ----
__global__ void k4b(const float* __restrict__ xl2,
                    const int* __restrict__ srcA, const int* __restrict__ dstA,
                    float* __restrict__ evbuf, const unsigned* __restrict__ amax,
                    float* __restrict__ denom, float* __restrict__ agg, int E, int Et) {
    int t = blockIdx.x * (blockDim.x >> 5) + (threadIdx.x >> 5);
    int c = threadIdx.x & 31;
    if (t >= Et) return;
    int s, d;
    if (t < E) { s = srcA[t]; d = dstA[t]; }
    else       { s = d = t - E; }
    float ev = expf(evbuf[t] - funkey(amax[d]));
    if (c == 0) { evbuf[t] = ev; atomAddF(&denom[d], ev); }
    atomAddF(&agg[(size_t)d * 32 + c], ev * xl2[(size_t)s * 32 + c]);
}

// ---- K4c: alpha output ----
__global__ void k4c(const float* __restrict__ evbuf, const int* __restrict__ dstA,
                    const float* __restrict__ denom, float* __restrict__ alpha, int E, int Et) {
    int t = blockIdx.x * blockDim.x + threadIdx.x;
    if (t >= Et) return;
    int d = (t < E) ? dstA[t] : (t - E);
    alpha[t] = evbuf[t] / (denom[d] + 1e-16f);
}

// ---- K5: out2 -> elu -> two MLP heads -> log_softmax -> out[N,30] ----
__global__ void k5(const float* __restrict__ agg, const float* __restrict__ denom,
                   const float* __restrict__ bias2,
                   const float* __restrict__ Wt1, const float* __restrict__ bt1,
                   const float* __restrict__ Wt2, const float* __restrict__ bt2,
                   const float* __restrict__ Wc1, const float* __restrict__ bc1,
                   const float* __restrict__ Wc2, const float* __restrict__ bc2,
                   float* __restrict__ out, int N) {
    __shared__ float sWt1[1024], sWc1[1024], sWt2[640], sWc2[320];
    __shared__ float sbt1[32], sbc1[32], sbt2[20], sbc2[10], sb2[32];
    for (int i = threadIdx.x; i < 1024; i += blockDim.x) { sWt1[i] = Wt1[i]; sWc1[i] = Wc1[i]; }
    for (int i = threadIdx.x; i < 640; i += blockDim.x) sWt2[i] = Wt2[i];
    for (int i = threadIdx.x; i < 320; i += blockDim.x) sWc2[i] = Wc2[i];
    if (threadIdx.x < 32) { sbt1[threadIdx.x] = bt1[threadIdx.x]; sbc1[threadIdx.x] = bc1[threadIdx.x]; sb2[threadIdx.x] = bias2[threadIdx.x]; }
    if (threadIdx.x < 20) sbt2[threadIdx.x] = bt2[threadIdx.x];
    if (threadIdx.x < 10) sbc2[threadIdx.x] = bc2[threadIdx.x];
    __syncthreads();
    int n = blockIdx.x * blockDim.x + threadIdx.x;
    if (n >= N) return;
    float dn = denom[n] + 1e-16f;
    float h[32];
    #pragma unroll
    for (int k = 0; k < 32; ++k) {
        float v = agg[(size_t)n * 32 + k] / dn + sb2[k];
        h[k] = elu1(v);
    }
    float t1[32], c1[32];
    #pragma unroll
    for (int j = 0; j < 32; ++j) {
        float at = sbt1[j], ac = sbc1[j];
        #pragma unroll
        for (int k = 0; k < 32; ++k) { at += h[k] * sWt1[k * 32 + j]; ac += h[k] * sWc1[k * 32 + j]; }
        t1[j] = fmaxf(at, 0.f);
        c1[j] = fmaxf(ac, 0.f);
    }
    float lt[20]; float mt = -1e30f;
    #pragma unroll
    for (int o = 0; o < 20; ++o) {
        float a = sbt2[o];
        #pragma unroll
        for (int k = 0; k < 32; ++k) a += t1[k] * sWt2[k * 20 + o];
        lt[o] = a; mt = fmaxf(mt, a);
    }
    float st = 0.f;
    #pragma unroll
    for (int o = 0; o < 20; ++o) st += expf(lt[o] - mt);
    float lset = mt + logf(st);
    float lc[10]; float mc = -1e30f;
    #pragma unroll
    for (int o = 0; o < 10; ++o) {
        float a = sbc2[o];
        #pragma unroll
        for (int k = 0; k < 32; ++k) a += c1[k] * sWc2[k * 10 + o];
        lc[o] = a; mc = fmaxf(mc, a);
    }
    float sc = 0.f;
    #pragma unroll
    for (int o = 0; o < 10; ++o) sc += expf(lc[o] - mc);
    float lsec = mc + logf(sc);
    #pragma unroll
    for (int o = 0; o < 10; ++o) out[(size_t)n * 30 + o] = lc[o] - lsec;
    #pragma unroll
    for (int o = 0; o < 20; ++o) out[(size_t)n * 30 + 10 + o] = lt[o] - lset;
}

extern "C" void kernel_launch(void* const* d_in, const int* in_sizes, int n_in,
                              void* d_out, int out_size, void* d_ws, size_t ws_size,
                              hipStream_t stream) {
    const float* x     = (const float*)d_in[0];
    const int*   ei    = (const int*)d_in[1];
    const float* eattr = (const float*)d_in[2];
    const float* Wl1   = (const float*)d_in[3];
    const float* bl1   = (const float*)d_in[4];
    const float* Wr1   = (const float*)d_in[5];
    const float* br1   = (const float*)d_in[6];
    const float* We1   = (const float*)d_in[7];
    const float* att1  = (const float*)d_in[8];
    const float* bias1 = (const float*)d_in[9];
    const float* skW   = (const float*)d_in[10];
    const float* skb   = (const float*)d_in[11];
    const float* gamma = (const float*)d_in[12];
    const float* beta  = (const float*)d_in[13];
    const float* Wl2   = (const float*)d_in[14];
    const float* bl2   = (const float*)d_in[15];
    const float* Wr2   = (const float*)d_in[16];
    const float* br2   = (const float*)d_in[17];
    const float* We2   = (const float*)d_in[18];
    const float* att2  = (const float*)d_in[19];
    const float* bias2 = (const float*)d_in[20];
    const float* Wc1   = (const float*)d_in[21];
    const float* bc1   = (const float*)d_in[22];
    const float* Wc2   = (const float*)d_in[23];
    const float* bc2   = (const float*)d_in[24];
    const float* Wt1   = (const float*)d_in[25];
    const float* bt1   = (const float*)d_in[26];
    const float* Wt2   = (const float*)d_in[27];
    const float* bt2   = (const float*)d_in[28];

    const int N  = in_sizes[0] / 2;
    const int E  = in_sizes[1] / 2;
    const int Et = E + N;
    const int* srcA = ei;
    const int* dstA = ei + E;

    // workspace layout (floats); total ~23.3M floats ~ 93 MB
    float* w = (float*)d_ws;
    float* xlA    = w; w += (size_t)N * 64;   // xl1, later xl2 (N*32)
    float* xrB    = w; w += (size_t)N * 64;   // xr1, later xr2 (N*32)
    float* aggC   = w; w += (size_t)N * 64;   // agg1 -> h_pre -> out2_unnorm (N*32)
    float* logitD = w; w += (size_t)Et * 2;   // logits1 -> logit2/expv2 (Et)
    float* amax   = w; w += (size_t)N * 2;    // uint keys
    float* denom  = w; w += (size_t)N * 2;
    float* deg    = w; w += N;
    float* lattr  = w; w += N;
    float* bnsum  = w; w += 64;
    float* bnsq   = w; w += 64;
    float* mu     = w; w += 64;
    float* rstd   = w; w += 64;

    float* outMain  = (float*)d_out;
    float* outAlpha = outMain + (size_t)N * 30;

    // ---- self-loop attr prep ----
    hipMemsetAsync(deg, 0, (size_t)2 * N * sizeof(float), stream);  // deg + lattr
    k0_deg<<<(E + 255) / 256, 256, 0, stream>>>(dstA, eattr, deg, lattr, E);
    k1_node<<<((size_t)N * 64 + 255) / 256, 256, 0, stream>>>(x, Wl1, bl1, Wr1, br1, deg, xlA, xrB, lattr, N);

    // ---- layer 1 ----
    hipMemsetAsync(amax, 0, (size_t)4 * N * sizeof(float), stream); // amax + denom
    hipMemsetAsync(aggC, 0, (size_t)N * 64 * sizeof(float), stream);
    k2a<<<(Et + 3) / 4, 256, 0, stream>>>(xlA, xrB, srcA, dstA, eattr, lattr, We1, att1,
                                          logitD, (unsigned*)amax, E, Et);
    k2b<<<(Et + 3) / 4, 256, 0, stream>>>(xlA, srcA, dstA, logitD, (const unsigned*)amax,
                                          denom, aggC, E, Et);

    // ---- skip + BN + ELU + layer-2 node transforms ----
    hipMemsetAsync(bnsum, 0, 128 * sizeof(float), stream);
    k3a<<<((size_t)N * 64 + 255) / 256, 256, 0, stream>>>(x, denom, bias1, skW, skb, aggC, bnsum, bnsq, N);
    k3b<<<1, 64, 0, stream>>>(bnsum, bnsq, mu, rstd, N);
    k3c<<<(N + 3) / 4, 256, 0, stream>>>(aggC, mu, rstd, gamma, beta, Wl2, bl2, Wr2, br2, xlA, xrB, N);

    // ---- layer 2 ----
    hipMemsetAsync(amax, 0, (size_t)4 * N * sizeof(float), stream); // amax2 + denom2
    hipMemsetAsync(aggC, 0, (size_t)N * 32 * sizeof(float), stream);
    k4a<<<(Et + 7) / 8, 256, 0, stream>>>(xlA, xrB, srcA, dstA, eattr, lattr, We2, att2,
                                          logitD, (unsigned*)amax, E, Et);
    k4b<<<(Et + 7) / 8, 256, 0, stream>>>(xlA, srcA, dstA, logitD, (const unsigned*)amax,
                                          denom, aggC, E, Et);
    k4c<<<(Et + 255) / 256, 256, 0, stream>>>(logitD, dstA, denom, outAlpha, E, Et);

    // ---- heads ----
    k5<<<(N + 255) / 256, 256, 0, stream>>>(aggC, denom, bias2, Wt1, bt1, Wt2, bt2,
                                            Wc1, bc1, Wc2, bc2, outMain, N);
    (void)n_in; (void)out_size; (void)ws_size;
}

// Round 2
// 1715.350 us; speedup vs baseline: 1.4483x; 1.4483x over previous
//
#include <hip/hip_runtime.h>
#include <math.h>

#define NEG_SLOPE 0.2f

__device__ __forceinline__ unsigned fkey(float f) {
    unsigned u = __float_as_uint(f);
    return (u & 0x80000000u) ? ~u : (u | 0x80000000u);
}
__device__ __forceinline__ float funkey(unsigned k) {
    unsigned u = (k & 0x80000000u) ? (k & 0x7FFFFFFFu) : ~k;
    return __uint_as_float(u);
}
__device__ __forceinline__ void atomAddF(float* p, float v) {
    unsafeAtomicAdd(p, v);  // HW global_atomic_add_f32
}
__device__ __forceinline__ float lrelu(float x) { return x > 0.f ? x : NEG_SLOPE * x; }
__device__ __forceinline__ float elu1(float x) { return x > 0.f ? x : expf(x) - 1.f; }

// ---- K0: in-degree + edge_attr sum per dst (self-loop attr 'mean') ----
__global__ void k0_deg(const int* __restrict__ dst, const float* __restrict__ ea,
                       float* __restrict__ deg, float* __restrict__ asum, int E) {
    int t = blockIdx.x * blockDim.x + threadIdx.x;
    if (t >= E) return;
    int d = dst[t];
    atomAddF(&deg[d], 1.0f);
    atomAddF(&asum[d], ea[t]);
}

// ---- K2a: layer-1 logits via rank-2 trick (thread per edge) ----
__global__ void k2a(const float* __restrict__ x,
                    const int* __restrict__ srcA, const int* __restrict__ dstA,
                    const float* __restrict__ ea, const float* __restrict__ asum,
                    const float* __restrict__ deg,
                    const float* __restrict__ Wl, const float* __restrict__ bl,
                    const float* __restrict__ Wr, const float* __restrict__ br,
                    const float* __restrict__ We, const float* __restrict__ att,
                    float* __restrict__ logit0, float* __restrict__ logit1,
                    unsigned* __restrict__ amax, int E, int Et) {
    __shared__ float sW[8][64];  // wl0,wl1,bl,wr0,wr1,br,we,att
    if (threadIdx.x < 64) {
        int d = threadIdx.x;
        sW[0][d] = Wl[d];  sW[1][d] = Wl[64 + d]; sW[2][d] = bl[d];
        sW[3][d] = Wr[d];  sW[4][d] = Wr[64 + d]; sW[5][d] = br[d];
        sW[6][d] = We[d];  sW[7][d] = att[d];
    }
    __syncthreads();
    int t = blockIdx.x * blockDim.x + threadIdx.x;
    if (t >= Et) return;
    int s, d; float eav;
    if (t < E) { s = srcA[t]; d = dstA[t]; eav = ea[t]; }
    else       { s = d = t - E; eav = asum[s] / fmaxf(deg[s], 1.0f); }
    float x0s = x[2 * s], x1s = x[2 * s + 1];
    float x0d = x[2 * d], x1d = x[2 * d + 1];
    float l0 = 0.f, l1 = 0.f;
    #pragma unroll
    for (int c = 0; c < 32; ++c) {
        float m0 = x0s * sW[0][c] + x1s * sW[1][c] + sW[2][c]
                 + x0d * sW[3][c] + x1d * sW[4][c] + sW[5][c] + eav * sW[6][c];
        l0 += lrelu(m0) * sW[7][c];
        int c2 = c + 32;
        float m1 = x0s * sW[0][c2] + x1s * sW[1][c2] + sW[2][c2]
                 + x0d * sW[3][c2] + x1d * sW[4][c2] + sW[5][c2] + eav * sW[6][c2];
        l1 += lrelu(m1) * sW[7][c2];
    }
    logit0[t] = l0; logit1[t] = l1;
    atomicMax(&amax[2 * d],     fkey(l0));
    atomicMax(&amax[2 * d + 1], fkey(l1));
}

// ---- K2b: expv + 6 scalar moments per edge (denom, ev*x0, ev*x1 per head) ----
__global__ void k2b(const float* __restrict__ x,
                    const int* __restrict__ srcA, const int* __restrict__ dstA,
                    const float* __restrict__ logit0, const float* __restrict__ logit1,
                    const unsigned* __restrict__ amax,
                    float* __restrict__ dstat, int E, int Et) {
    int t = blockIdx.x * blockDim.x + threadIdx.x;
    if (t >= Et) return;
    int s, d;
    if (t < E) { s = srcA[t]; d = dstA[t]; }
    else       { s = d = t - E; }
    float ev0 = expf(logit0[t] - funkey(amax[2 * d]));
    float ev1 = expf(logit1[t] - funkey(amax[2 * d + 1]));
    float x0s = x[2 * s], x1s = x[2 * s + 1];
    float* p = &dstat[(size_t)d * 6];
    atomAddF(p + 0, ev0);        atomAddF(p + 1, ev1);
    atomAddF(p + 2, ev0 * x0s);  atomAddF(p + 3, ev1 * x0s);
    atomAddF(p + 4, ev0 * x1s);  atomAddF(p + 5, ev1 * x1s);
}

// ---- K3a: reconstruct h = agg/denom + bias1 + skip; BN partials (no global contention) ----
__global__ void k3a(const float* __restrict__ x, const float* __restrict__ dstat,
                    const float* __restrict__ Wl, const float* __restrict__ bl,
                    const float* __restrict__ bias1,
                    const float* __restrict__ skW, const float* __restrict__ skb,
                    float* __restrict__ hout, float* __restrict__ partial, int N) {
    __shared__ float sv[256], sq[256];
    size_t total = (size_t)N * 64;
    size_t stride = (size_t)gridDim.x * blockDim.x;   // multiple of 64 -> d fixed per thread
    float s = 0.f, q = 0.f;
    for (size_t idx = (size_t)blockIdx.x * blockDim.x + threadIdx.x; idx < total; idx += stride) {
        int n = (int)(idx >> 6), d = (int)(idx & 63), h2 = d >> 5;
        const float* ps = &dstat[(size_t)n * 6];
        float den = ps[h2], t0 = ps[2 + h2], t1 = ps[4 + h2];
        float agg = t0 * Wl[d] + t1 * Wl[64 + d] + den * bl[d];
        float hv = agg / (den + 1e-16f) + bias1[d]
                 + x[2 * n] * skW[d] + x[2 * n + 1] * skW[64 + d] + skb[d];
        hout[idx] = hv;
        s += hv; q += hv * hv;
    }
    sv[threadIdx.x] = s; sq[threadIdx.x] = q;
    __syncthreads();
    if (threadIdx.x < 64) {
        float a = sv[threadIdx.x] + sv[threadIdx.x + 64] + sv[threadIdx.x + 128] + sv[threadIdx.x + 192];
        float b = sq[threadIdx.x] + sq[threadIdx.x + 64] + sq[threadIdx.x + 128] + sq[threadIdx.x + 192];
        partial[(size_t)blockIdx.x * 128 + threadIdx.x] = a;
        partial[(size_t)blockIdx.x * 128 + 64 + threadIdx.x] = b;
    }
}

// ---- Kred: reduce per-block BN partials (128 columns) ----
__global__ void kred(const float* __restrict__ partial, float* __restrict__ bnstat, int G) {
    __shared__ float sm[256];
    int c = blockIdx.x;  // 0..127
    float s = 0.f;
    for (int i = threadIdx.x; i < G; i += blockDim.x) s += partial[(size_t)i * 128 + c];
    sm[threadIdx.x] = s;
    __syncthreads();
    for (int off = 128; off >= 1; off >>= 1) {
        if (threadIdx.x < off) sm[threadIdx.x] += sm[threadIdx.x + off];
        __syncthreads();
    }
    if (threadIdx.x == 0) bnstat[c] = sm[0];
}

// ---- K3b: mu, rstd ----
__global__ void k3b(const float* __restrict__ bnsum, const float* __restrict__ bnsq,
                    float* __restrict__ mu, float* __restrict__ rstd, int N) {
    int d = threadIdx.x;
    float m = bnsum[d] / (float)N;
    float v = bnsq[d] / (float)N - m * m;
    mu[d] = m;
    rstd[d] = rsqrtf(v + 1e-5f);
}

// ---- K3c: BN + ELU -> xl2 = h@Wl2+bl2, xr2 = h@Wr2+br2 (wave per node) ----
__global__ void k3c(const float* __restrict__ h, const float* __restrict__ mu,
                    const float* __restrict__ rstd, const float* __restrict__ gamma,
                    const float* __restrict__ beta,
                    const float* __restrict__ Wl, const float* __restrict__ bl,
                    const float* __restrict__ Wr, const float* __restrict__ br,
                    float* __restrict__ xl2, float* __restrict__ xr2, int N) {
    __shared__ float sh[4][64];
    int w = threadIdx.x >> 6, lane = threadIdx.x & 63;
    int n = blockIdx.x * 4 + w;
    bool valid = (n < N);
    if (valid) {
        float hv = h[(size_t)n * 64 + lane];
        hv = (hv - mu[lane]) * rstd[lane] * gamma[lane] + beta[lane];
        sh[w][lane] = elu1(hv);
    }
    __syncthreads();
    if (!valid) return;
    int c = lane & 31;
    const float* W = (lane < 32) ? Wl : Wr;
    const float* b = (lane < 32) ? bl : br;
    float acc = b[c];
    #pragma unroll
    for (int k = 0; k < 64; ++k) acc += sh[w][k] * W[k * 32 + c];
    ((lane < 32) ? xl2 : xr2)[(size_t)n * 32 + c] = acc;
}

// ---- K4a: layer-2 logits + segment max (2 edges per wave, 32 lanes each) ----
__global__ void k4a(const float* __restrict__ xl2, const float* __restrict__ xr2,
                    const int* __restrict__ srcA, const int* __restrict__ dstA,
                    const float* __restrict__ ea, const float* __restrict__ asum,
                    const float* __restrict__ deg,
                    const float* __restrict__ We, const float* __restrict__ att,
                    float* __restrict__ logit, unsigned* __restrict__ amax,
                    int E, int Et) {
    int t = blockIdx.x * (blockDim.x >> 5) + (threadIdx.x >> 5);
    int c = threadIdx.x & 31;
    if (t >= Et) return;
    int s, d; float eav;
    if (t < E) { s = srcA[t]; d = dstA[t]; eav = ea[t]; }
    else       { s = d = t - E; eav = asum[s] / fmaxf(deg[s], 1.0f); }
    float m = xl2[(size_t)s * 32 + c] + xr2[(size_t)d * 32 + c] + eav * We[c];
    m = lrelu(m);
    float p = m * att[c];
    p += __shfl_xor(p, 16);
    p += __shfl_xor(p, 8);
    p += __shfl_xor(p, 4);
    p += __shfl_xor(p, 2);
    p += __shfl_xor(p, 1);
    if (c == 0) {
        logit[t] = p;
        atomicMax(&amax[d], fkey(p));
    }
}

// ---- K4b: expv (stored in place of logit), denom, agg ----
__global__ void k4b(const float* __restrict__ xl2,
                    const int* __restrict__ srcA, const int* __restrict__ dstA,
                    float* __restrict__ evbuf, const unsigned* __restrict__ amax,
                    float* __restrict__ denom, float* __restrict__ agg, int E, int Et) {
    int t = blockIdx.x * (blockDim.x >> 5) + (threadIdx.x >> 5);
    int c = threadIdx.x & 31;
    if (t >= Et) return;
    int s, d;
    if (t < E) { s = srcA[t]; d = dstA[t]; }
    else       { s = d = t - E; }
    float ev = expf(evbuf[t] - funkey(amax[d]));
    if (c == 0) { evbuf[t] = ev; atomAddF(&denom[d], ev); }
    atomAddF(&agg[(size_t)d * 32 + c], ev * xl2[(size_t)s * 32 + c]);
}

// ---- K4c: alpha output ----
__global__ void k4c(const float* __restrict__ evbuf, const int* __restrict__ dstA,
                    const float* __restrict__ denom, float* __restrict__ alpha, int E, int Et) {
    int t = blockIdx.x * blockDim.x + threadIdx.x;
    if (t >= Et) return;
    int d = (t < E) ? dstA[t] : (t - E);
    alpha[t] = evbuf[t] / (denom[d] + 1e-16f);
}

// ---- K5: out2 -> elu -> two MLP heads -> log_softmax -> out[N,30] ----
__global__ void k5(const float* __restrict__ agg, const float* __restrict__ denom,
                   const float* __restrict__ bias2,
                   const float* __restrict__ Wt1, const float* __restrict__ bt1,
                   const float* __restrict__ Wt2, const float* __restrict__ bt2,
                   const float* __restrict__ Wc1, const float* __restrict__ bc1,
                   const float* __restrict__ Wc2, const float* __restrict__ bc2,
                   float* __restrict__ out, int N) {
    __shared__ float sWt1[1024], sWc1[1024], sWt2[640], sWc2[320];
    __shared__ float sbt1[32], sbc1[32], sbt2[20], sbc2[10], sb2[32];
    for (int i = threadIdx.x; i < 1024; i += blockDim.x) { sWt1[i] = Wt1[i]; sWc1[i] = Wc1[i]; }
    for (int i = threadIdx.x; i < 640; i += blockDim.x) sWt2[i] = Wt2[i];
    for (int i = threadIdx.x; i < 320; i += blockDim.x) sWc2[i] = Wc2[i];
    if (threadIdx.x < 32) { sbt1[threadIdx.x] = bt1[threadIdx.x]; sbc1[threadIdx.x] = bc1[threadIdx.x]; sb2[threadIdx.x] = bias2[threadIdx.x]; }
    if (threadIdx.x < 20) sbt2[threadIdx.x] = bt2[threadIdx.x];
    if (threadIdx.x < 10) sbc2[threadIdx.x] = bc2[threadIdx.x];
    __syncthreads();
    int n = blockIdx.x * blockDim.x + threadIdx.x;
    if (n >= N) return;
    float dn = denom[n] + 1e-16f;
    float h[32];
    #pragma unroll
    for (int k = 0; k < 32; ++k) {
        float v = agg[(size_t)n * 32 + k] / dn + sb2[k];
        h[k] = elu1(v);
    }
    float t1[32], c1[32];
    #pragma unroll
    for (int j = 0; j < 32; ++j) {
        float at = sbt1[j], ac = sbc1[j];
        #pragma unroll
        for (int k = 0; k < 32; ++k) { at += h[k] * sWt1[k * 32 + j]; ac += h[k] * sWc1[k * 32 + j]; }
        t1[j] = fmaxf(at, 0.f);
        c1[j] = fmaxf(ac, 0.f);
    }
    float lt[20]; float mt = -1e30f;
    #pragma unroll
    for (int o = 0; o < 20; ++o) {
        float a = sbt2[o];
        #pragma unroll
        for (int k = 0; k < 32; ++k) a += t1[k] * sWt2[k * 20 + o];
        lt[o] = a; mt = fmaxf(mt, a);
    }
    float st = 0.f;
    #pragma unroll
    for (int o = 0; o < 20; ++o) st += expf(lt[o] - mt);
    float lset = mt + logf(st);
    float lc[10]; float mc = -1e30f;
    #pragma unroll
    for (int o = 0; o < 10; ++o) {
        float a = sbc2[o];
        #pragma unroll
        for (int k = 0; k < 32; ++k) a += c1[k] * sWc2[k * 10 + o];
        lc[o] = a; mc = fmaxf(mc, a);
    }
    float sc = 0.f;
    #pragma unroll
    for (int o = 0; o < 10; ++o) sc += expf(lc[o] - mc);
    float lsec = mc + logf(sc);
    #pragma unroll
    for (int o = 0; o < 10; ++o) out[(size_t)n * 30 + o] = lc[o] - lsec;
    #pragma unroll
    for (int o = 0; o < 20; ++o) out[(size_t)n * 30 + 10 + o] = lt[o] - lset;
}

extern "C" void kernel_launch(void* const* d_in, const int* in_sizes, int n_in,
                              void* d_out, int out_size, void* d_ws, size_t ws_size,
                              hipStream_t stream) {
    const float* x     = (const float*)d_in[0];
    const int*   ei    = (const int*)d_in[1];
    const float* eattr = (const float*)d_in[2];
    const float* Wl1   = (const float*)d_in[3];
    const float* bl1   = (const float*)d_in[4];
    const float* Wr1   = (const float*)d_in[5];
    const float* br1   = (const float*)d_in[6];
    const float* We1   = (const float*)d_in[7];
    const float* att1  = (const float*)d_in[8];
    const float* bias1 = (const float*)d_in[9];
    const float* skW   = (const float*)d_in[10];
    const float* skb   = (const float*)d_in[11];
    const float* gamma = (const float*)d_in[12];
    const float* beta  = (const float*)d_in[13];
    const float* Wl2   = (const float*)d_in[14];
    const float* bl2   = (const float*)d_in[15];
    const float* Wr2   = (const float*)d_in[16];
    const float* br2   = (const float*)d_in[17];
    const float* We2   = (const float*)d_in[18];
    const float* att2  = (const float*)d_in[19];
    const float* bias2 = (const float*)d_in[20];
    const float* Wc1   = (const float*)d_in[21];
    const float* bc1   = (const float*)d_in[22];
    const float* Wc2   = (const float*)d_in[23];
    const float* bc2   = (const float*)d_in[24];
    const float* Wt1   = (const float*)d_in[25];
    const float* bt1   = (const float*)d_in[26];
    const float* Wt2   = (const float*)d_in[27];
    const float* bt2   = (const float*)d_in[28];

    const int N  = in_sizes[0] / 2;
    const int E  = in_sizes[1] / 2;
    const int Et = E + N;
    const int* srcA = ei;
    const int* dstA = ei + E;
    const int G3 = 1024;

    // workspace layout (floats)
    float* w = (float*)d_ws;
    float* hbuf   = w; w += (size_t)N * 64;
    float* xl2    = w; w += (size_t)N * 32;
    float* xr2    = w; w += (size_t)N * 32;
    float* agg2   = w; w += (size_t)N * 32;   // agg2 + denom2 contiguous for one memset
    float* denom2 = w; w += N;
    float* logit0 = w; w += Et;
    float* logit1 = w; w += Et;
    float* amax   = w; w += (size_t)2 * N;    // amax + dstat contiguous for one memset
    float* dstat  = w; w += (size_t)6 * N;
    float* deg    = w; w += N;                // deg + asum contiguous
    float* asum   = w; w += N;
    float* partial= w; w += (size_t)G3 * 128;
    float* bnstat = w; w += 128;
    float* mu     = w; w += 64;
    float* rstd   = w; w += 64;

    float* outMain  = (float*)d_out;
    float* outAlpha = outMain + (size_t)N * 30;

    // ---- self-loop attr prep ----
    hipMemsetAsync(deg, 0, (size_t)2 * N * sizeof(float), stream);   // deg + asum
    k0_deg<<<(E + 255) / 256, 256, 0, stream>>>(dstA, eattr, deg, asum, E);

    // ---- layer 1 (rank-2 factored) ----
    hipMemsetAsync(amax, 0, (size_t)8 * N * sizeof(float), stream);  // amax + dstat
    k2a<<<(Et + 255) / 256, 256, 0, stream>>>(x, srcA, dstA, eattr, asum, deg,
                                              Wl1, bl1, Wr1, br1, We1, att1,
                                              logit0, logit1, (unsigned*)amax, E, Et);
    k2b<<<(Et + 255) / 256, 256, 0, stream>>>(x, srcA, dstA, logit0, logit1,
                                              (const unsigned*)amax, dstat, E, Et);

    // ---- node reconstruction + skip + BN stats ----
    k3a<<<G3, 256, 0, stream>>>(x, dstat, Wl1, bl1, bias1, skW, skb, hbuf, partial, N);
    kred<<<128, 256, 0, stream>>>(partial, bnstat, G3);
    k3b<<<1, 64, 0, stream>>>(bnstat, bnstat + 64, mu, rstd, N);
    k3c<<<(N + 3) / 4, 256, 0, stream>>>(hbuf, mu, rstd, gamma, beta,
                                         Wl2, bl2, Wr2, br2, xl2, xr2, N);

    // ---- layer 2 ----
    hipMemsetAsync(amax, 0, (size_t)N * sizeof(float), stream);          // amax (1 head)
    hipMemsetAsync(agg2, 0, (size_t)N * 33 * sizeof(float), stream);     // agg2 + denom2
    k4a<<<(Et + 7) / 8, 256, 0, stream>>>(xl2, xr2, srcA, dstA, eattr, asum, deg,
                                          We2, att2, logit0, (unsigned*)amax, E, Et);
    k4b<<<(Et + 7) / 8, 256, 0, stream>>>(xl2, srcA, dstA, logit0, (const unsigned*)amax,
                                          denom2, agg2, E, Et);
    k4c<<<(Et + 255) / 256, 256, 0, stream>>>(logit0, dstA, denom2, outAlpha, E, Et);

    // ---- heads ----
    k5<<<(N + 255) / 256, 256, 0, stream>>>(agg2, denom2, bias2, Wt1, bt1, Wt2, bt2,
                                            Wc1, bc1, Wc2, bc2, outMain, N);
    (void)n_in; (void)out_size; (void)ws_size;
}